// Round 12
// baseline (83.583 us; speedup 1.0000x reference)
//
#include <hip/hip_runtime.h>
#include <hip/hip_bf16.h>
#include <math.h>

namespace {
constexpr int kB = 8;
constexpr int kN = 2048;
constexpr int kC = 512;
constexpr int kR = kB * kN;          // 16384 rows total
constexpr int kNC = 2 * kC;          // 1024 concatenated output cols
constexpr float kInvSqrtC = 0.044194173824159216f; // 1/sqrt(512)

typedef __attribute__((ext_vector_type(8))) short short8;
typedef __attribute__((ext_vector_type(4))) short short4b;
typedef __attribute__((ext_vector_type(4))) float f32x4;
typedef unsigned short ushort;
}

static __device__ __forceinline__ float bf2f(ushort u) {
  union { unsigned int i; float f; } v; v.i = (unsigned int)u << 16; return v.f;
}
static __device__ __forceinline__ ushort f2bf(float f) {
  __hip_bfloat16 h = __float2bfloat16(f);
  union { __hip_bfloat16 h; ushort u; } cv; cv.h = h; return cv.u;
}

#define GLOAD16(G, L) __builtin_amdgcn_global_load_lds( \
    (const __attribute__((address_space(1))) unsigned int*)(G), \
    (__attribute__((address_space(3))) unsigned int*)(L), 16, 0, 0)

// ---------- castw: weight casts + hist/compaction + bias dots (all from fp32 originals) ----------
// z=0: WqT=Wq^T; z=1: WkT=Wk^T; z=2: WvT=Wv^T; z=3: Woh=Wo (cast);
// z=4 (block 0,0): neighbor histogram + compaction -> jlist/cnt_c/meta;
// z=5: bias dots: gid<2 ubk->biascat[0:512); gid<4 vbq; gid<12 bvo->biascat[512:1024); gid==12 bqbk.
__global__ __launch_bounds__(256) void castw_kernel(
    const float* __restrict__ Wq, const float* __restrict__ Wk,
    const float* __restrict__ Wv, const float* __restrict__ Wo,
    ushort* __restrict__ WqT, ushort* __restrict__ WkT,
    ushort* __restrict__ WvT, ushort* __restrict__ Woh,
    const int* __restrict__ nbr,
    int* __restrict__ jlist, int* __restrict__ cnt_c, int* __restrict__ meta,
    const float* __restrict__ bq, const float* __restrict__ bk, const float* __restrict__ bv,
    float* __restrict__ biascat, float* __restrict__ vbq, float* __restrict__ bqbk) {
  const int z = blockIdx.z;
  const int t = threadIdx.x;
  if (z == 5) {
    const int gid = blockIdx.y * 8 + blockIdx.x;
    if (gid < 2) {                       // ubk[c] = sum_d Wq[d,c]*bk[d]  (coalesced over c)
      const int c = gid * 256 + t;
      float s = 0.f;
#pragma unroll 8
      for (int d = 0; d < kC; d++) s += Wq[d * kC + c] * bk[d];
      biascat[c] = s;
    } else if (gid < 4) {                // vbq[c] = sum_d Wk[d,c]*bq[d]
      const int c = (gid - 2) * 256 + t;
      float s = 0.f;
#pragma unroll 8
      for (int d = 0; d < kC; d++) s += Wk[d * kC + c] * bq[d];
      vbq[c] = s;
    } else if (gid < 12) {               // bvo[d] = sum_c Wo[d,c]*bv[c]  (wave-per-row)
      const int w = t >> 6, lane = t & 63;
      const int dbase = (gid - 4) * 64 + w * 16;
      const float4 v0 = *reinterpret_cast<const float4*>(&bv[lane * 8]);
      const float4 v1 = *reinterpret_cast<const float4*>(&bv[lane * 8 + 4]);
      for (int i = 0; i < 16; i++) {
        const int d = dbase + i;
        const float4 a0 = *reinterpret_cast<const float4*>(&Wo[(size_t)d * kC + lane * 8]);
        const float4 a1 = *reinterpret_cast<const float4*>(&Wo[(size_t)d * kC + lane * 8 + 4]);
        float s = a0.x * v0.x + a0.y * v0.y + a0.z * v0.z + a0.w * v0.w +
                  a1.x * v1.x + a1.y * v1.y + a1.z * v1.z + a1.w * v1.w;
#pragma unroll
        for (int off = 32; off; off >>= 1) s += __shfl_xor(s, off);
        if (lane == 0) biascat[kC + d] = s;
      }
    } else if (gid == 12 && t < 64) {    // bqbk = bq.bk
      const float4 q0 = *reinterpret_cast<const float4*>(&bq[t * 8]);
      const float4 q1 = *reinterpret_cast<const float4*>(&bq[t * 8 + 4]);
      const float4 k0 = *reinterpret_cast<const float4*>(&bk[t * 8]);
      const float4 k1 = *reinterpret_cast<const float4*>(&bk[t * 8 + 4]);
      float s = q0.x * k0.x + q0.y * k0.y + q0.z * k0.z + q0.w * k0.w +
                q1.x * k1.x + q1.y * k1.y + q1.z * k1.z + q1.w * k1.w;
#pragma unroll
      for (int off = 32; off; off >>= 1) s += __shfl_xor(s, off);
      if (t == 0) bqbk[0] = s;
    }
    return;
  }
  if (z == 4) {
    if (blockIdx.x || blockIdx.y) return;
    __shared__ int h[kN];
    __shared__ int wsum[256];
#pragma unroll
    for (int i = 0; i < 8; i++) h[t + i * 256] = 0;
    __syncthreads();
#pragma unroll
    for (int i = 0; i < 8; i++) atomicAdd(&h[nbr[t + i * 256]], 1);
    __syncthreads();
    // --- compaction: thread t owns j in [t*8, t*8+8) ---
    const int base = t * 8;
    int lpre[8], lc = 0;
#pragma unroll
    for (int i = 0; i < 8; i++) { lpre[i] = lc; lc += (h[base + i] > 0) ? 1 : 0; }
    wsum[t] = lc;
    __syncthreads();
    for (int off = 1; off < 256; off <<= 1) {   // Hillis-Steele inclusive scan
      const int v = (t >= off) ? wsum[t - off] : 0;
      __syncthreads();
      wsum[t] += v;
      __syncthreads();
    }
    const int excl = (t == 0) ? 0 : wsum[t - 1];
    const int total = wsum[255];
#pragma unroll
    for (int i = 0; i < 8; i++) {
      if (h[base + i] > 0) {
        const int p = excl + lpre[i];
        jlist[p] = base + i;
        cnt_c[p] = h[base + i];
      }
    }
    for (int p = total + t; p < kN; p += 256) { jlist[p] = 0; cnt_c[p] = 0; }
    if (t == 0) meta[0] = total;
    return;
  }
  const int d0 = blockIdx.x * 64, c0 = blockIdx.y * 64;
  if (z == 3) {
#pragma unroll
    for (int i = 0; i < 4; i++) {
      const int row = i * 16 + (t >> 4), col4 = (t & 15) * 4;
      const float4 v = *reinterpret_cast<const float4*>(&Wo[(d0 + row) * kC + c0 + col4]);
      short4b o;
      o[0] = (short)f2bf(v.x); o[1] = (short)f2bf(v.y);
      o[2] = (short)f2bf(v.z); o[3] = (short)f2bf(v.w);
      *reinterpret_cast<short4b*>(&Woh[(d0 + row) * kC + c0 + col4]) = o;
    }
    return;
  }
  __shared__ float ld[64][65];
  const float* S = (z == 0) ? Wq : ((z == 1) ? Wk : Wv);
  ushort* T = (z == 0) ? WqT : ((z == 1) ? WkT : WvT);
#pragma unroll
  for (int i = 0; i < 4; i++) {
    const int dl = i * 16 + (t >> 4), cl4 = (t & 15) * 4;
    const float4 v = *reinterpret_cast<const float4*>(&S[(d0 + dl) * kC + c0 + cl4]);
    ld[dl][cl4 + 0] = v.x; ld[dl][cl4 + 1] = v.y;
    ld[dl][cl4 + 2] = v.z; ld[dl][cl4 + 3] = v.w;
  }
  __syncthreads();
#pragma unroll
  for (int i = 0; i < 4; i++) {
    const int cl = i * 16 + (t >> 4), dl4 = (t & 15) * 4;
    short4b o;
#pragma unroll
    for (int q = 0; q < 4; q++) o[q] = (short)f2bf(ld[dl4 + q][cl]);
    *reinterpret_cast<short4b*>(&T[(size_t)(c0 + cl) * kC + d0 + dl4]) = o;
  }
}

// ---------- foldg: MFMA weight folds + x-cast + g (fold hides under cast's memory streaming) ----------
// z=0 -> Bh[0:512) = A = WqT @ WkT^T ; z=1 -> Bh[512:1024) = Wo @ WvT^T ;
// z>=2 -> castg unit (z-2)*64 + by*8 + bx: 4 rows of x->xh + g[r]=x[r].vbq
__global__ __launch_bounds__(256) void foldg_kernel(
    const ushort* __restrict__ WqT, const ushort* __restrict__ WkT,
    const ushort* __restrict__ Woh, const ushort* __restrict__ WvT,
    ushort* __restrict__ Bh,
    const float* __restrict__ x, const float* __restrict__ vbq,
    ushort* __restrict__ xh, float* __restrict__ g) {
  const int t = threadIdx.x, lane = t & 63, w = t >> 6;
  const int z = blockIdx.z;
  if (z >= 2) {
    const int unit = (z - 2) * 64 + blockIdx.y * 8 + blockIdx.x;
    const int r = unit * 4 + w;
    const float4 a = *reinterpret_cast<const float4*>(&x[(size_t)r * kC + lane * 8]);
    const float4 b = *reinterpret_cast<const float4*>(&x[(size_t)r * kC + lane * 8 + 4]);
    short8 o;
    o[0] = (short)f2bf(a.x); o[1] = (short)f2bf(a.y);
    o[2] = (short)f2bf(a.z); o[3] = (short)f2bf(a.w);
    o[4] = (short)f2bf(b.x); o[5] = (short)f2bf(b.y);
    o[6] = (short)f2bf(b.z); o[7] = (short)f2bf(b.w);
    *reinterpret_cast<short8*>(&xh[(size_t)r * kC + lane * 8]) = o;
    const float4 v0 = *reinterpret_cast<const float4*>(&vbq[lane * 8]);
    const float4 v1 = *reinterpret_cast<const float4*>(&vbq[lane * 8 + 4]);
    float acc = a.x * v0.x + a.y * v0.y + a.z * v0.z + a.w * v0.w +
                b.x * v1.x + b.y * v1.y + b.z * v1.z + b.w * v1.w;
#pragma unroll
    for (int off = 32; off; off >>= 1) acc += __shfl_xor(acc, off);
    if (lane == 0) g[r] = acc;
    return;
  }
  __shared__ ushort lA[64 * 64];
  __shared__ ushort lB[64 * 64];
  const ushort* Ap = z ? Woh : WqT;
  const ushort* Bp = z ? WvT : WkT;
  const int r0 = blockIdx.y * 64, c0 = blockIdx.x * 64;
  const int wr = (w >> 1) * 32, wc = (w & 1) * 32;
  const int srow = t >> 3, scol = (t & 7) * 8;
  f32x4 acc[2][2] = {};
  for (int k0 = 0; k0 < kC; k0 += 64) {
#pragma unroll
    for (int it = 0; it < 2; it++) {
      GLOAD16(&Ap[(size_t)(r0 + it * 32 + srow) * kC + k0 + scol], &lA[(it * 32 + srow) * 64 + scol]);
      GLOAD16(&Bp[(size_t)(c0 + it * 32 + srow) * kC + k0 + scol], &lB[(it * 32 + srow) * 64 + scol]);
    }
    __syncthreads();
#pragma unroll
    for (int kk = 0; kk < 2; kk++) {
      const int ko = kk * 32 + (lane >> 4) * 8;
      short8 af[2], bfr[2];
#pragma unroll
      for (int i = 0; i < 2; i++)
        af[i] = *reinterpret_cast<const short8*>(&lA[(wr + i * 16 + (lane & 15)) * 64 + ko]);
#pragma unroll
      for (int j = 0; j < 2; j++)
        bfr[j] = *reinterpret_cast<const short8*>(&lB[(wc + j * 16 + (lane & 15)) * 64 + ko]);
#pragma unroll
      for (int i = 0; i < 2; i++)
#pragma unroll
        for (int j = 0; j < 2; j++)
          acc[i][j] = __builtin_amdgcn_mfma_f32_16x16x32_bf16(af[i], bfr[j], acc[i][j], 0, 0, 0);
    }
    __syncthreads();
  }
#pragma unroll
  for (int j = 0; j < 2; j++) {
    const int col = c0 + wc + j * 16 + (lane & 15);
#pragma unroll
    for (int i = 0; i < 2; i++) {
      const int rbase = r0 + wr + i * 16 + (lane >> 4) * 4;
#pragma unroll
      for (int q = 0; q < 4; q++)
        Bh[(size_t)(z * kC + rbase + q) * kC + col] = f2bf(acc[i][j][q]);
    }
  }
}

// ---------- big fused GEMM on COMPACTED rows (sync-dbuf) + SVO epilogue (r11, proven) ----------
__global__ __launch_bounds__(256) void mm_kernel(
    const ushort* __restrict__ xh, const ushort* __restrict__ Bh,
    const float* __restrict__ biascat,
    const int* __restrict__ cnt_c, const int* __restrict__ jlist, const int* __restrict__ meta,
    ushort* __restrict__ obuf, float* __restrict__ part2) {
  __shared__ ushort lA[2][128 * 64];
  __shared__ ushort lB[2][128 * 64];
  __shared__ float cs[2][128];
  const int id = blockIdx.x;
  const int orig = (id & 7) * 128 + (id >> 3);     // XCD-aware swizzle (1024 % 8 == 0)
  const int rt = orig >> 3;                        // 0..127
  const int c0 = (orig & 7) * 128;
  const int b = rt >> 4, lt = rt & 15;
  const int t = threadIdx.x;
  const bool isVo = (c0 >= 512);                   // block-uniform
  if (lt * 128 >= meta[0]) {                       // tile entirely beyond compacted rows
    if (isVo && t < 128)
      part2[(size_t)(b * 16 + lt) * kC + (c0 - 512) + t] = 0.f;
    return;
  }
  const int lane = t & 63, w = t >> 6;
  const int wr = (w >> 1) * 64, wc = (w & 1) * 64;
  const int srow = t >> 3, scol = (t & 7) * 8;
  int jl[4];
#pragma unroll
  for (int it = 0; it < 4; it++) jl[it] = jlist[lt * 128 + it * 32 + srow];
  f32x4 acc[4][4] = {};

  auto stage = [&](int buf, int k0) {
#pragma unroll
    for (int it = 0; it < 4; it++) {
      GLOAD16(&xh[(size_t)(b * kN + jl[it]) * kC + k0 + scol],
              &lA[buf][(it * 32 + srow) * 64 + scol]);
      GLOAD16(&Bh[(size_t)(c0 + it * 32 + srow) * kC + k0 + scol],
              &lB[buf][(it * 32 + srow) * 64 + scol]);
    }
  };

  stage(0, 0);
  __syncthreads();
  int cur = 0;
#pragma unroll
  for (int ts = 0; ts < 8; ++ts) {
    if (ts < 7) stage(cur ^ 1, (ts + 1) * 64);     // prefetch flies under MFMA
#pragma unroll
    for (int kk = 0; kk < 2; kk++) {
      const int ko = kk * 32 + (lane >> 4) * 8;
      short8 af[4], bfr[4];
#pragma unroll
      for (int i = 0; i < 4; i++)
        af[i] = *reinterpret_cast<const short8*>(&lA[cur][(wr + i * 16 + (lane & 15)) * 64 + ko]);
#pragma unroll
      for (int j = 0; j < 4; j++)
        bfr[j] = *reinterpret_cast<const short8*>(&lB[cur][(wc + j * 16 + (lane & 15)) * 64 + ko]);
      __builtin_amdgcn_s_setprio(1);
#pragma unroll
      for (int i = 0; i < 4; i++)
#pragma unroll
        for (int j = 0; j < 4; j++)
          acc[i][j] = __builtin_amdgcn_mfma_f32_16x16x32_bf16(af[i], bfr[j], acc[i][j], 0, 0, 0);
      __builtin_amdgcn_s_setprio(0);
    }
    __syncthreads();
    cur ^= 1;
  }

  // ---- epilogue: bias add, svo partial (cnt_c), scattered stores to original rows ----
  const int cbase = lt * 128 + wr + ((lane >> 4) << 2);
  float cw[4][4];
  int rj[4][4];
#pragma unroll
  for (int i = 0; i < 4; i++) {
    const int4 j4 = *reinterpret_cast<const int4*>(&jlist[cbase + i * 16]);
    rj[i][0] = j4.x; rj[i][1] = j4.y; rj[i][2] = j4.z; rj[i][3] = j4.w;
  }
  if (isVo) {
#pragma unroll
    for (int i = 0; i < 4; i++) {
      const int4 c4 = *reinterpret_cast<const int4*>(&cnt_c[cbase + i * 16]);
      cw[i][0] = (float)c4.x; cw[i][1] = (float)c4.y;
      cw[i][2] = (float)c4.z; cw[i][3] = (float)c4.w;
    }
  }
  float psum[4] = {0.f, 0.f, 0.f, 0.f};
#pragma unroll
  for (int j = 0; j < 4; j++) {
    const int col = c0 + wc + j * 16 + (lane & 15);
    const float bias = biascat[col];
#pragma unroll
    for (int i = 0; i < 4; i++) {
#pragma unroll
      for (int q = 0; q < 4; q++) {
        const float v = acc[i][j][q] + bias;
        obuf[(size_t)(b * kN + rj[i][q]) * kNC + col] = f2bf(v);
        if (isVo) psum[j] += v * cw[i][q];
      }
    }
  }
  if (isVo) {
#pragma unroll
    for (int j = 0; j < 4; j++) {
      psum[j] += __shfl_xor(psum[j], 16);
      psum[j] += __shfl_xor(psum[j], 32);
    }
    if (lane < 16) {
#pragma unroll
      for (int j = 0; j < 4; j++) cs[w >> 1][wc + j * 16 + lane] = psum[j];
    }
    __syncthreads();
    if (t < 128) {
      part2[(size_t)(b * 16 + lt) * kC + (c0 - 512) + t] = cs[0][t] + cs[1][t];
    }
  }
}

// ---------- svo[b,d] = sum_{rt<16} part2[b,rt,d] ----------
__global__ __launch_bounds__(256) void svo_reduce_kernel(
    const float* __restrict__ part2, float* __restrict__ svo) {
  const int d = blockIdx.x * 256 + threadIdx.x;  // 2 blocks
  const int b = blockIdx.y;                      // 8
  float a = 0.f;
#pragma unroll
  for (int rt = 0; rt < 16; rt++) a += part2[(size_t)(b * 16 + rt) * kC + d];
  svo[b * kC + d] = a;
}

// ---------- final: s = xh_n . w_j + g_j + bqbk + rb; out = inv*SVO + coef*VO[j2] + bo ----------
__global__ __launch_bounds__(256) void final_kernel(
    const ushort* __restrict__ xh, const ushort* __restrict__ obuf,
    const float* __restrict__ svo, const float* __restrict__ g, const int* __restrict__ nbr,
    const float* __restrict__ bqbk, const float* __restrict__ rb, const float* __restrict__ bo,
    float* __restrict__ out) {
  const int wid = threadIdx.x >> 6, lane = threadIdx.x & 63;
  const int rg = blockIdx.x * 4 + wid;
  const int b = rg >> 11, n = rg & (kN - 1);
  const int j = nbr[n];
  const int j2 = nbr[j];
  const short8 xv = *reinterpret_cast<const short8*>(&xh[(size_t)rg * kC + lane * 8]);
  const short8 wv = *reinterpret_cast<const short8*>(&obuf[(size_t)(b * kN + j) * kNC + lane * 8]);
  float a = 0.f;
#pragma unroll
  for (int q = 0; q < 8; q++) a += bf2f((ushort)xv[q]) * bf2f((ushort)wv[q]);
#pragma unroll
  for (int off = 32; off; off >>= 1) a += __shfl_xor(a, off);
  const float s = a + g[b * kN + j] + bqbk[0] + rb[0];
  const float tt = s * kInvSqrtC;
  const float e = expf(tt);
  const float inv = 1.0f / (e + (float)(kN - 1));
  const float coef = (e - 1.0f) * inv;
  const short8 vv = *reinterpret_cast<const short8*>(&obuf[(size_t)(b * kN + j2) * kNC + kC + lane * 8]);
  const float4 s0 = *reinterpret_cast<const float4*>(&svo[b * kC + lane * 8]);
  const float4 s1 = *reinterpret_cast<const float4*>(&svo[b * kC + lane * 8 + 4]);
  const float4 b0 = *reinterpret_cast<const float4*>(&bo[lane * 8]);
  const float4 b1 = *reinterpret_cast<const float4*>(&bo[lane * 8 + 4]);
  float4 r0, r1;
  r0.x = s0.x * inv + bf2f((ushort)vv[0]) * coef + b0.x;
  r0.y = s0.y * inv + bf2f((ushort)vv[1]) * coef + b0.y;
  r0.z = s0.z * inv + bf2f((ushort)vv[2]) * coef + b0.z;
  r0.w = s0.w * inv + bf2f((ushort)vv[3]) * coef + b0.w;
  r1.x = s1.x * inv + bf2f((ushort)vv[4]) * coef + b1.x;
  r1.y = s1.y * inv + bf2f((ushort)vv[5]) * coef + b1.y;
  r1.z = s1.z * inv + bf2f((ushort)vv[6]) * coef + b1.z;
  r1.w = s1.w * inv + bf2f((ushort)vv[7]) * coef + b1.w;
  *reinterpret_cast<float4*>(&out[(size_t)rg * kC + lane * 8]) = r0;
  *reinterpret_cast<float4*>(&out[(size_t)rg * kC + lane * 8 + 4]) = r1;
}

extern "C" void kernel_launch(void* const* d_in, const int* in_sizes, int n_in,
                              void* d_out, int out_size, void* d_ws, size_t ws_size,
                              hipStream_t stream) {
  const float* x  = (const float*)d_in[0];
  const int* nbr  = (const int*)d_in[1];
  const float* Wq = (const float*)d_in[2];
  const float* bq = (const float*)d_in[3];
  const float* Wk = (const float*)d_in[4];
  const float* bk = (const float*)d_in[5];
  const float* Wv = (const float*)d_in[6];
  const float* bv = (const float*)d_in[7];
  const float* rb = (const float*)d_in[8];
  const float* Wo = (const float*)d_in[9];
  const float* bo = (const float*)d_in[10];
  float* out = (float*)d_out;

  char* ws = (char*)d_ws;
  size_t off = 0;
  auto alloc = [&](size_t bytes) -> void* {
    void* p = ws + off;
    off = (off + bytes + 255) & ~(size_t)255;
    return p;
  };
  ushort* xh    = (ushort*)alloc((size_t)kR * kC * 2);
  ushort* Bh    = (ushort*)alloc((size_t)kNC * kC * 2);
  ushort* obuf  = (ushort*)alloc((size_t)kR * kNC * 2);
  ushort* WqT   = (ushort*)alloc((size_t)kC * kC * 2);
  ushort* WkT   = (ushort*)alloc((size_t)kC * kC * 2);
  ushort* WvT   = (ushort*)alloc((size_t)kC * kC * 2);
  ushort* Woh   = (ushort*)alloc((size_t)kC * kC * 2);
  float* biascat = (float*)alloc(kNC * 4);
  float* vbq    = (float*)alloc(kC * 4);
  float* bqbk   = (float*)alloc(4);
  int*   jlist  = (int*)alloc(kN * 4);
  int*   cnt_c  = (int*)alloc(kN * 4);
  int*   meta   = (int*)alloc(256);
  float* g      = (float*)alloc((size_t)kR * 4);
  float* svo    = (float*)alloc((size_t)kB * kC * 4);
  float* part2  = (float*)alloc((size_t)kB * 16 * kC * 4);
  (void)ws_size; (void)n_in; (void)in_sizes; (void)out_size;

  castw_kernel<<<dim3(8, 8, 6), 256, 0, stream>>>(Wq, Wk, Wv, Wo, WqT, WkT, WvT, Woh,
                                                  nbr, jlist, cnt_c, meta,
                                                  bq, bk, bv, biascat, vbq, bqbk);
  foldg_kernel<<<dim3(8, 8, 66), 256, 0, stream>>>(WqT, WkT, Woh, WvT, Bh, x, vbq, xh, g);
  mm_kernel<<<1024, 256, 0, stream>>>(xh, Bh, biascat, cnt_c, jlist, meta, obuf, part2);
  svo_reduce_kernel<<<dim3(2, kB), 256, 0, stream>>>(part2, svo);
  final_kernel<<<kR / 4, 256, 0, stream>>>(xh, obuf, svo, g, nbr, bqbk, rb, bo, out);
}

// Round 13
// 67.849 us; speedup vs baseline: 1.2319x; 1.2319x over previous
//
#include <hip/hip_runtime.h>
#include <hip/hip_bf16.h>
#include <math.h>

namespace {
constexpr int kB = 8;
constexpr int kN = 2048;
constexpr int kC = 512;
constexpr int kR = kB * kN;          // 16384 rows total
constexpr int kNC = 2 * kC;          // 1024 concatenated output cols
constexpr float kInvSqrtC = 0.044194173824159216f; // 1/sqrt(512)

typedef __attribute__((ext_vector_type(8))) short short8;
typedef __attribute__((ext_vector_type(4))) short short4b;
typedef __attribute__((ext_vector_type(4))) float f32x4;
typedef unsigned short ushort;
}

static __device__ __forceinline__ float bf2f(ushort u) {
  union { unsigned int i; float f; } v; v.i = (unsigned int)u << 16; return v.f;
}
static __device__ __forceinline__ ushort f2bf(float f) {
  __hip_bfloat16 h = __float2bfloat16(f);
  union { __hip_bfloat16 h; ushort u; } cv; cv.h = h; return cv.u;
}

#define GLOAD16(G, L) __builtin_amdgcn_global_load_lds( \
    (const __attribute__((address_space(1))) unsigned int*)(G), \
    (__attribute__((address_space(3))) unsigned int*)(L), 16, 0, 0)

// ---------- weights fp32 -> bf16 (3 transposed + 1 straight) + hist + compaction ----------
// z=0: WqT[c][d]=Wq[d][c]; z=1: WkT[e][d]=Wk[d][e]; z=2: WvT[e][c]=Wv[c][e]; z=3: Woh=Wo;
// z=4 (block 0,0 only): neighbor histogram -> cnt; compact {j : cnt[j]>0} -> jlist/cnt_c/meta.
__global__ __launch_bounds__(256) void castw_kernel(
    const float* __restrict__ Wq, const float* __restrict__ Wk,
    const float* __restrict__ Wv, const float* __restrict__ Wo,
    ushort* __restrict__ WqT, ushort* __restrict__ WkT,
    ushort* __restrict__ WvT, ushort* __restrict__ Woh,
    const int* __restrict__ nbr, int* __restrict__ cnt,
    int* __restrict__ jlist, int* __restrict__ cnt_c, int* __restrict__ meta) {
  const int z = blockIdx.z;
  const int t = threadIdx.x;
  if (z == 4) {
    if (blockIdx.x || blockIdx.y) return;
    __shared__ int h[kN];
    __shared__ int wsum[256];
#pragma unroll
    for (int i = 0; i < 8; i++) h[t + i * 256] = 0;
    __syncthreads();
#pragma unroll
    for (int i = 0; i < 8; i++) atomicAdd(&h[nbr[t + i * 256]], 1);
    __syncthreads();
#pragma unroll
    for (int i = 0; i < 8; i++) cnt[t + i * 256] = h[t + i * 256];
    // --- compaction: thread t owns j in [t*8, t*8+8) ---
    const int base = t * 8;
    int lpre[8], lc = 0;
#pragma unroll
    for (int i = 0; i < 8; i++) { lpre[i] = lc; lc += (h[base + i] > 0) ? 1 : 0; }
    wsum[t] = lc;
    __syncthreads();
    for (int off = 1; off < 256; off <<= 1) {   // Hillis-Steele inclusive scan
      const int v = (t >= off) ? wsum[t - off] : 0;
      __syncthreads();
      wsum[t] += v;
      __syncthreads();
    }
    const int excl = (t == 0) ? 0 : wsum[t - 1];
    const int total = wsum[255];
#pragma unroll
    for (int i = 0; i < 8; i++) {
      if (h[base + i] > 0) {
        const int p = excl + lpre[i];
        jlist[p] = base + i;
        cnt_c[p] = h[base + i];
      }
    }
    for (int p = total + t; p < kN; p += 256) { jlist[p] = 0; cnt_c[p] = 0; }
    if (t == 0) meta[0] = total;
    return;
  }
  const int d0 = blockIdx.x * 64, c0 = blockIdx.y * 64;
  if (z == 3) {
#pragma unroll
    for (int i = 0; i < 4; i++) {
      const int row = i * 16 + (t >> 4), col4 = (t & 15) * 4;
      const float4 v = *reinterpret_cast<const float4*>(&Wo[(d0 + row) * kC + c0 + col4]);
      short4b o;
      o[0] = (short)f2bf(v.x); o[1] = (short)f2bf(v.y);
      o[2] = (short)f2bf(v.z); o[3] = (short)f2bf(v.w);
      *reinterpret_cast<short4b*>(&Woh[(d0 + row) * kC + c0 + col4]) = o;
    }
    return;
  }
  __shared__ float ld[64][65];
  const float* S = (z == 0) ? Wq : ((z == 1) ? Wk : Wv);
  ushort* T = (z == 0) ? WqT : ((z == 1) ? WkT : WvT);
#pragma unroll
  for (int i = 0; i < 4; i++) {
    const int dl = i * 16 + (t >> 4), cl4 = (t & 15) * 4;
    const float4 v = *reinterpret_cast<const float4*>(&S[(d0 + dl) * kC + c0 + cl4]);
    ld[dl][cl4 + 0] = v.x; ld[dl][cl4 + 1] = v.y;
    ld[dl][cl4 + 2] = v.z; ld[dl][cl4 + 3] = v.w;
  }
  __syncthreads();
#pragma unroll
  for (int i = 0; i < 4; i++) {
    const int cl = i * 16 + (t >> 4), dl4 = (t & 15) * 4;
    short4b o;
#pragma unroll
    for (int q = 0; q < 4; q++) o[q] = (short)f2bf(ld[dl4 + q][cl]);
    *reinterpret_cast<short4b*>(&T[(size_t)(c0 + cl) * kC + d0 + dl4]) = o;
  }
}

// ---------- MFMA fold + bias folds ----------
// z=0 -> Bh[0:512) = A = WqT @ WkT^T ; z=1 -> Bh[512:1024) = Wo @ WvT^T ; z=2 -> bias dots
__global__ __launch_bounds__(256) void fold_kernel(
    const ushort* __restrict__ WqT, const ushort* __restrict__ WkT,
    const ushort* __restrict__ Woh, const ushort* __restrict__ WvT,
    ushort* __restrict__ Bh,
    const float* __restrict__ bq, const float* __restrict__ bk, const float* __restrict__ bv,
    float* __restrict__ biascat, float* __restrict__ vbq, float* __restrict__ bqbk) {
  const int t = threadIdx.x, lane = t & 63, w = t >> 6;
  const int z = blockIdx.z;
  if (z == 2) {
    const int fid = blockIdx.y * 8 + blockIdx.x;     // 0..63
    const int gw = fid * 4 + w;                      // 0..255
    for (int rr = gw; rr < 1536; rr += 256) {
      const ushort* rowp; const float* vec;
      if (rr < 512)       { rowp = &WqT[(size_t)rr * kC];          vec = bk; }
      else if (rr < 1024) { rowp = &WkT[(size_t)(rr - 512) * kC];  vec = bq; }
      else                { rowp = &Woh[(size_t)(rr - 1024) * kC]; vec = bv; }
      const short8 u = *reinterpret_cast<const short8*>(&rowp[lane * 8]);
      const float4 v0 = *reinterpret_cast<const float4*>(&vec[lane * 8]);
      const float4 v1 = *reinterpret_cast<const float4*>(&vec[lane * 8 + 4]);
      float a = bf2f((ushort)u[0]) * v0.x + bf2f((ushort)u[1]) * v0.y +
                bf2f((ushort)u[2]) * v0.z + bf2f((ushort)u[3]) * v0.w +
                bf2f((ushort)u[4]) * v1.x + bf2f((ushort)u[5]) * v1.y +
                bf2f((ushort)u[6]) * v1.z + bf2f((ushort)u[7]) * v1.w;
#pragma unroll
      for (int off = 32; off; off >>= 1) a += __shfl_xor(a, off);
      if (lane == 0) {
        if (rr < 512) biascat[rr] = a;
        else if (rr < 1024) vbq[rr - 512] = a;
        else biascat[rr - 512] = a;
      }
    }
    if (gw == 0) {
      const float4 q0 = *reinterpret_cast<const float4*>(&bq[lane * 8]);
      const float4 q1 = *reinterpret_cast<const float4*>(&bq[lane * 8 + 4]);
      const float4 k0 = *reinterpret_cast<const float4*>(&bk[lane * 8]);
      const float4 k1 = *reinterpret_cast<const float4*>(&bk[lane * 8 + 4]);
      float s = q0.x * k0.x + q0.y * k0.y + q0.z * k0.z + q0.w * k0.w +
                q1.x * k1.x + q1.y * k1.y + q1.z * k1.z + q1.w * k1.w;
#pragma unroll
      for (int off = 32; off; off >>= 1) s += __shfl_xor(s, off);
      if (lane == 0) bqbk[0] = s;
    }
    return;
  }
  __shared__ ushort lA[64 * 64];
  __shared__ ushort lB[64 * 64];
  const ushort* Ap = z ? Woh : WqT;
  const ushort* Bp = z ? WvT : WkT;
  const int r0 = blockIdx.y * 64, c0 = blockIdx.x * 64;
  const int wr = (w >> 1) * 32, wc = (w & 1) * 32;
  const int srow = t >> 3, scol = (t & 7) * 8;
  f32x4 acc[2][2] = {};
  for (int k0 = 0; k0 < kC; k0 += 64) {
#pragma unroll
    for (int it = 0; it < 2; it++) {
      GLOAD16(&Ap[(size_t)(r0 + it * 32 + srow) * kC + k0 + scol], &lA[(it * 32 + srow) * 64 + scol]);
      GLOAD16(&Bp[(size_t)(c0 + it * 32 + srow) * kC + k0 + scol], &lB[(it * 32 + srow) * 64 + scol]);
    }
    __syncthreads();
#pragma unroll
    for (int kk = 0; kk < 2; kk++) {
      const int ko = kk * 32 + (lane >> 4) * 8;
      short8 af[2], bfr[2];
#pragma unroll
      for (int i = 0; i < 2; i++)
        af[i] = *reinterpret_cast<const short8*>(&lA[(wr + i * 16 + (lane & 15)) * 64 + ko]);
#pragma unroll
      for (int j = 0; j < 2; j++)
        bfr[j] = *reinterpret_cast<const short8*>(&lB[(wc + j * 16 + (lane & 15)) * 64 + ko]);
#pragma unroll
      for (int i = 0; i < 2; i++)
#pragma unroll
        for (int j = 0; j < 2; j++)
          acc[i][j] = __builtin_amdgcn_mfma_f32_16x16x32_bf16(af[i], bfr[j], acc[i][j], 0, 0, 0);
    }
    __syncthreads();
  }
#pragma unroll
  for (int j = 0; j < 2; j++) {
    const int col = c0 + wc + j * 16 + (lane & 15);
#pragma unroll
    for (int i = 0; i < 2; i++) {
      const int rbase = r0 + wr + i * 16 + (lane >> 4) * 4;
#pragma unroll
      for (int q = 0; q < 4; q++)
        Bh[(size_t)(z * kC + rbase + q) * kC + col] = f2bf(acc[i][j][q]);
    }
  }
}

// ---------- fused: x (fp32) -> xh (bf16) AND g[r] = dot(x[r,:], vbq) ----------
__global__ __launch_bounds__(256) void castg_kernel(
    const float* __restrict__ x, const float* __restrict__ vbq,
    ushort* __restrict__ xh, float* __restrict__ g) {
  const int wid = threadIdx.x >> 6, lane = threadIdx.x & 63;
  const int r = blockIdx.x * 4 + wid;
  const float4 a = *reinterpret_cast<const float4*>(&x[(size_t)r * kC + lane * 8]);
  const float4 b = *reinterpret_cast<const float4*>(&x[(size_t)r * kC + lane * 8 + 4]);
  short8 o;
  o[0] = (short)f2bf(a.x); o[1] = (short)f2bf(a.y);
  o[2] = (short)f2bf(a.z); o[3] = (short)f2bf(a.w);
  o[4] = (short)f2bf(b.x); o[5] = (short)f2bf(b.y);
  o[6] = (short)f2bf(b.z); o[7] = (short)f2bf(b.w);
  *reinterpret_cast<short8*>(&xh[(size_t)r * kC + lane * 8]) = o;
  const float4 v0 = *reinterpret_cast<const float4*>(&vbq[lane * 8]);
  const float4 v1 = *reinterpret_cast<const float4*>(&vbq[lane * 8 + 4]);
  float acc = a.x * v0.x + a.y * v0.y + a.z * v0.z + a.w * v0.w +
              b.x * v1.x + b.y * v1.y + b.z * v1.z + b.w * v1.w;
#pragma unroll
  for (int off = 32; off; off >>= 1) acc += __shfl_xor(acc, off);
  if (lane == 0) g[r] = acc;
}

// ---------- big fused GEMM on COMPACTED rows (sync-dbuf, r8 structure) + SVO epilogue ----------
// Row-tile rt = orig>>3 -> batch b = rt>>4, local tile lt = rt&15 over compacted jlist.
// obuf stores go to ORIGINAL row indices b*kN + jlist[...] -> final kernel unchanged.
__global__ __launch_bounds__(256) void mm_kernel(
    const ushort* __restrict__ xh, const ushort* __restrict__ Bh,
    const float* __restrict__ biascat,
    const int* __restrict__ cnt_c, const int* __restrict__ jlist, const int* __restrict__ meta,
    ushort* __restrict__ obuf, float* __restrict__ part2) {
  __shared__ ushort lA[2][128 * 64];
  __shared__ ushort lB[2][128 * 64];
  __shared__ float cs[2][128];
  const int id = blockIdx.x;
  const int orig = (id & 7) * 128 + (id >> 3);     // XCD-aware swizzle (1024 % 8 == 0)
  const int rt = orig >> 3;                        // 0..127
  const int c0 = (orig & 7) * 128;
  const int b = rt >> 4, lt = rt & 15;
  const int t = threadIdx.x;
  const bool isVo = (c0 >= 512);                   // block-uniform
  if (lt * 128 >= meta[0]) {                       // tile entirely beyond compacted rows
    if (isVo && t < 128)
      part2[(size_t)(b * 16 + lt) * kC + (c0 - 512) + t] = 0.f;
    return;
  }
  const int lane = t & 63, w = t >> 6;
  const int wr = (w >> 1) * 64, wc = (w & 1) * 64;
  const int srow = t >> 3, scol = (t & 7) * 8;
  int jl[4];
#pragma unroll
  for (int it = 0; it < 4; it++) jl[it] = jlist[lt * 128 + it * 32 + srow];
  f32x4 acc[4][4] = {};

  auto stage = [&](int buf, int k0) {
#pragma unroll
    for (int it = 0; it < 4; it++) {
      GLOAD16(&xh[(size_t)(b * kN + jl[it]) * kC + k0 + scol],
              &lA[buf][(it * 32 + srow) * 64 + scol]);
      GLOAD16(&Bh[(size_t)(c0 + it * 32 + srow) * kC + k0 + scol],
              &lB[buf][(it * 32 + srow) * 64 + scol]);
    }
  };

  stage(0, 0);
  __syncthreads();
  int cur = 0;
#pragma unroll
  for (int ts = 0; ts < 8; ++ts) {
    if (ts < 7) stage(cur ^ 1, (ts + 1) * 64);     // prefetch flies under MFMA
#pragma unroll
    for (int kk = 0; kk < 2; kk++) {
      const int ko = kk * 32 + (lane >> 4) * 8;
      short8 af[4], bfr[4];
#pragma unroll
      for (int i = 0; i < 4; i++)
        af[i] = *reinterpret_cast<const short8*>(&lA[cur][(wr + i * 16 + (lane & 15)) * 64 + ko]);
#pragma unroll
      for (int j = 0; j < 4; j++)
        bfr[j] = *reinterpret_cast<const short8*>(&lB[cur][(wc + j * 16 + (lane & 15)) * 64 + ko]);
      __builtin_amdgcn_s_setprio(1);
#pragma unroll
      for (int i = 0; i < 4; i++)
#pragma unroll
        for (int j = 0; j < 4; j++)
          acc[i][j] = __builtin_amdgcn_mfma_f32_16x16x32_bf16(af[i], bfr[j], acc[i][j], 0, 0, 0);
      __builtin_amdgcn_s_setprio(0);
    }
    __syncthreads();
    cur ^= 1;
  }

  // ---- epilogue: bias add, svo partial (cnt_c), scattered stores to original rows ----
  const int cbase = lt * 128 + wr + ((lane >> 4) << 2);
  float cw[4][4];
  int rj[4][4];
#pragma unroll
  for (int i = 0; i < 4; i++) {
    const int4 j4 = *reinterpret_cast<const int4*>(&jlist[cbase + i * 16]);
    rj[i][0] = j4.x; rj[i][1] = j4.y; rj[i][2] = j4.z; rj[i][3] = j4.w;
  }
  if (isVo) {
#pragma unroll
    for (int i = 0; i < 4; i++) {
      const int4 c4 = *reinterpret_cast<const int4*>(&cnt_c[cbase + i * 16]);
      cw[i][0] = (float)c4.x; cw[i][1] = (float)c4.y;
      cw[i][2] = (float)c4.z; cw[i][3] = (float)c4.w;
    }
  }
  float psum[4] = {0.f, 0.f, 0.f, 0.f};
#pragma unroll
  for (int j = 0; j < 4; j++) {
    const int col = c0 + wc + j * 16 + (lane & 15);
    const float bias = biascat[col];
#pragma unroll
    for (int i = 0; i < 4; i++) {
#pragma unroll
      for (int q = 0; q < 4; q++) {
        const float v = acc[i][j][q] + bias;
        obuf[(size_t)(b * kN + rj[i][q]) * kNC + col] = f2bf(v);
        if (isVo) psum[j] += v * cw[i][q];
      }
    }
  }
  if (isVo) {
#pragma unroll
    for (int j = 0; j < 4; j++) {
      psum[j] += __shfl_xor(psum[j], 16);
      psum[j] += __shfl_xor(psum[j], 32);
    }
    if (lane < 16) {
#pragma unroll
      for (int j = 0; j < 4; j++) cs[w >> 1][wc + j * 16 + lane] = psum[j];
    }
    __syncthreads();
    if (t < 128) {
      part2[(size_t)(b * 16 + lt) * kC + (c0 - 512) + t] = cs[0][t] + cs[1][t];
    }
  }
}

// ---------- svo[b,d] = sum_{rt<16} part2[b,rt,d] ----------
__global__ __launch_bounds__(256) void svo_reduce_kernel(
    const float* __restrict__ part2, float* __restrict__ svo) {
  const int d = blockIdx.x * 256 + threadIdx.x;  // 2 blocks
  const int b = blockIdx.y;                      // 8
  float a = 0.f;
#pragma unroll
  for (int rt = 0; rt < 16; rt++) a += part2[(size_t)(b * 16 + rt) * kC + d];
  svo[b * kC + d] = a;
}

// ---------- final: s = xh_n . w_j + g_j + bqbk + rb; out = inv*SVO + coef*VO[j2] + bo ----------
__global__ __launch_bounds__(256) void final_kernel(
    const ushort* __restrict__ xh, const ushort* __restrict__ obuf,
    const float* __restrict__ svo, const float* __restrict__ g, const int* __restrict__ nbr,
    const float* __restrict__ bqbk, const float* __restrict__ rb, const float* __restrict__ bo,
    float* __restrict__ out) {
  const int wid = threadIdx.x >> 6, lane = threadIdx.x & 63;
  const int rg = blockIdx.x * 4 + wid;
  const int b = rg >> 11, n = rg & (kN - 1);
  const int j = nbr[n];
  const int j2 = nbr[j];
  const short8 xv = *reinterpret_cast<const short8*>(&xh[(size_t)rg * kC + lane * 8]);
  const short8 wv = *reinterpret_cast<const short8*>(&obuf[(size_t)(b * kN + j) * kNC + lane * 8]);
  float a = 0.f;
#pragma unroll
  for (int q = 0; q < 8; q++) a += bf2f((ushort)xv[q]) * bf2f((ushort)wv[q]);
#pragma unroll
  for (int off = 32; off; off >>= 1) a += __shfl_xor(a, off);
  const float s = a + g[b * kN + j] + bqbk[0] + rb[0];
  const float tt = s * kInvSqrtC;
  const float e = expf(tt);
  const float inv = 1.0f / (e + (float)(kN - 1));
  const float coef = (e - 1.0f) * inv;
  const short8 vv = *reinterpret_cast<const short8*>(&obuf[(size_t)(b * kN + j2) * kNC + kC + lane * 8]);
  const float4 s0 = *reinterpret_cast<const float4*>(&svo[b * kC + lane * 8]);
  const float4 s1 = *reinterpret_cast<const float4*>(&svo[b * kC + lane * 8 + 4]);
  const float4 b0 = *reinterpret_cast<const float4*>(&bo[lane * 8]);
  const float4 b1 = *reinterpret_cast<const float4*>(&bo[lane * 8 + 4]);
  float4 r0, r1;
  r0.x = s0.x * inv + bf2f((ushort)vv[0]) * coef + b0.x;
  r0.y = s0.y * inv + bf2f((ushort)vv[1]) * coef + b0.y;
  r0.z = s0.z * inv + bf2f((ushort)vv[2]) * coef + b0.z;
  r0.w = s0.w * inv + bf2f((ushort)vv[3]) * coef + b0.w;
  r1.x = s1.x * inv + bf2f((ushort)vv[4]) * coef + b1.x;
  r1.y = s1.y * inv + bf2f((ushort)vv[5]) * coef + b1.y;
  r1.z = s1.z * inv + bf2f((ushort)vv[6]) * coef + b1.z;
  r1.w = s1.w * inv + bf2f((ushort)vv[7]) * coef + b1.w;
  *reinterpret_cast<float4*>(&out[(size_t)rg * kC + lane * 8]) = r0;
  *reinterpret_cast<float4*>(&out[(size_t)rg * kC + lane * 8 + 4]) = r1;
}

extern "C" void kernel_launch(void* const* d_in, const int* in_sizes, int n_in,
                              void* d_out, int out_size, void* d_ws, size_t ws_size,
                              hipStream_t stream) {
  const float* x  = (const float*)d_in[0];
  const int* nbr  = (const int*)d_in[1];
  const float* Wq = (const float*)d_in[2];
  const float* bq = (const float*)d_in[3];
  const float* Wk = (const float*)d_in[4];
  const float* bk = (const float*)d_in[5];
  const float* Wv = (const float*)d_in[6];
  const float* bv = (const float*)d_in[7];
  const float* rb = (const float*)d_in[8];
  const float* Wo = (const float*)d_in[9];
  const float* bo = (const float*)d_in[10];
  float* out = (float*)d_out;

  char* ws = (char*)d_ws;
  size_t off = 0;
  auto alloc = [&](size_t bytes) -> void* {
    void* p = ws + off;
    off = (off + bytes + 255) & ~(size_t)255;
    return p;
  };
  ushort* xh    = (ushort*)alloc((size_t)kR * kC * 2);
  ushort* Bh    = (ushort*)alloc((size_t)kNC * kC * 2);
  ushort* obuf  = (ushort*)alloc((size_t)kR * kNC * 2);
  ushort* WqT   = (ushort*)alloc((size_t)kC * kC * 2);
  ushort* WkT   = (ushort*)alloc((size_t)kC * kC * 2);
  ushort* WvT   = (ushort*)alloc((size_t)kC * kC * 2);
  ushort* Woh   = (ushort*)alloc((size_t)kC * kC * 2);
  float* biascat = (float*)alloc(kNC * 4);
  float* vbq    = (float*)alloc(kC * 4);
  float* bqbk   = (float*)alloc(4);
  int*   cnt    = (int*)alloc(kN * 4);
  int*   jlist  = (int*)alloc(kN * 4);
  int*   cnt_c  = (int*)alloc(kN * 4);
  int*   meta   = (int*)alloc(256);
  float* g      = (float*)alloc((size_t)kR * 4);
  float* svo    = (float*)alloc((size_t)kB * kC * 4);
  float* part2  = (float*)alloc((size_t)kB * 16 * kC * 4);
  (void)ws_size; (void)n_in; (void)in_sizes; (void)out_size;

  castw_kernel<<<dim3(8, 8, 5), 256, 0, stream>>>(Wq, Wk, Wv, Wo, WqT, WkT, WvT, Woh,
                                                  nbr, cnt, jlist, cnt_c, meta);
  fold_kernel<<<dim3(8, 8, 3), 256, 0, stream>>>(WqT, WkT, Woh, WvT, Bh, bq, bk, bv, biascat, vbq, bqbk);
  castg_kernel<<<kR / 4, 256, 0, stream>>>(x, vbq, xh, g);
  mm_kernel<<<1024, 256, 0, stream>>>(xh, Bh, biascat, cnt_c, jlist, meta, obuf, part2);
  svo_reduce_kernel<<<dim3(2, kB), 256, 0, stream>>>(part2, svo);
  final_kernel<<<kR / 4, 256, 0, stream>>>(xh, obuf, svo, g, nbr, bqbk, rb, bo, out);
}